// Round 1
// baseline (139.243 us; speedup 1.0000x reference)
//
#include <hip/hip_runtime.h>

// Regularized Wasserstein (Sinkhorn, eps=0.2, 50 iters) on 64x64 images, b=64.
// Key identity: K = G (x) G  (separable Gibbs kernel), G[i,k]=exp(-5(i-k)^2),
// which is numerically banded with radius 2 in fp32 (next tap e^-45 ~ 2.9e-20).
// So v@K.T == G*V*G (5-tap separable conv). K*C = G2(x)G + G(x)G2 with
// G2[i,k] = (i-k)^2 * G[i,k]. One block per batch image; whole 50-iter loop in LDS.

#define PITCH 65   // 64 + 1 pad: column reads (stride 65) -> bank (r+c)%32, 2-way max

__device__ __forceinline__ void conv_col(const float* __restrict__ src,
                                         int c, int r0,
                                         float t0, float t1, float t2,
                                         float out[16])
{
    // out[k] = sum_d tap[|d|] * src[r0+k+d][c], d in [-2,2], zero-padded edges
    float w[20];
#pragma unroll
    for (int k = 0; k < 20; ++k) {
        int rr = r0 + k - 2;
        w[k] = (rr >= 0 && rr < 64) ? src[rr * PITCH + c] : 0.0f;
    }
#pragma unroll
    for (int k = 0; k < 16; ++k) {
        out[k] = t2 * (w[k] + w[k + 4]) + t1 * (w[k + 1] + w[k + 3]) + t0 * w[k + 2];
    }
}

extern "C" __global__ void __launch_bounds__(256)
sinkhorn_kernel(const float* __restrict__ x, const float* __restrict__ y,
                const float* __restrict__ cost, const float* __restrict__ kern,
                float* __restrict__ partials)
{
    __shared__ float bufV[64 * PITCH];
    __shared__ float bufU[64 * PITCH];
    __shared__ float bufA[64 * PITCH];
    __shared__ float wsum[4];

    const int b  = blockIdx.x;
    const int t  = threadIdx.x;
    const int c  = t & 63;         // lane: column of src in each pass
    const int r0 = (t >> 6) * 16;  // wave: 16-row strip

    // Taps taken from the actual input buffers (bitwise identical to reference):
    // G[i,k] = kern[(i*64)*4096 + (k*64)]
    const float g1 = kern[(size_t)64  * 4096];   // e^-5
    const float g2 = kern[(size_t)128 * 4096];   // e^-20
    const float q1 = cost[(size_t)64  * 4096] * g1;  // 1 * e^-5
    const float q2 = cost[(size_t)128 * 4096] * g2;  // 4 * e^-20

    // Preload this thread's x,y row segment (matches its pass-2 output tile).
    float xr[16], yr[16];
    {
        const float* xb = x + (size_t)b * 4096 + c * 64 + r0;
        const float* yb = y + (size_t)b * 4096 + c * 64 + r0;
#pragma unroll
        for (int k = 0; k < 16; ++k) { xr[k] = xb[k]; yr[k] = yb[k]; }
    }

    // V init = 1/n
#pragma unroll
    for (int k = 0; k < 16; ++k) bufV[c * PITCH + r0 + k] = 1.0f / 4096.0f;
    __syncthreads();

    float o[16];
    for (int it = 0; it < 50; ++it) {
        // U = x / (G V G + 1e-8)
        conv_col(bufV, c, r0, 1.0f, g1, g2, o);
#pragma unroll
        for (int k = 0; k < 16; ++k) bufA[c * PITCH + r0 + k] = o[k];
        __syncthreads();
        conv_col(bufA, c, r0, 1.0f, g1, g2, o);
#pragma unroll
        for (int k = 0; k < 16; ++k) bufU[c * PITCH + r0 + k] = xr[k] / (o[k] + 1e-8f);
        __syncthreads();
        // V = y / (G U G + 1e-8)
        conv_col(bufU, c, r0, 1.0f, g1, g2, o);
#pragma unroll
        for (int k = 0; k < 16; ++k) bufA[c * PITCH + r0 + k] = o[k];
        __syncthreads();
        conv_col(bufA, c, r0, 1.0f, g1, g2, o);
#pragma unroll
        for (int k = 0; k < 16; ++k) bufV[c * PITCH + r0 + k] = yr[k] / (o[k] + 1e-8f);
        __syncthreads();
    }

    // distance contribution: sum U o (G2 V G)  +  sum U o (G V G2)
    float acc = 0.0f;

    conv_col(bufV, c, r0, 0.0f, q1, q2, o);          // G2 applied on rows
#pragma unroll
    for (int k = 0; k < 16; ++k) bufA[c * PITCH + r0 + k] = o[k];
    __syncthreads();
    conv_col(bufA, c, r0, 1.0f, g1, g2, o);          // then G on cols -> G2*V*G
#pragma unroll
    for (int k = 0; k < 16; ++k) acc += bufU[c * PITCH + r0 + k] * o[k];
    __syncthreads();

    conv_col(bufV, c, r0, 1.0f, g1, g2, o);          // G on rows
#pragma unroll
    for (int k = 0; k < 16; ++k) bufA[c * PITCH + r0 + k] = o[k];
    __syncthreads();
    conv_col(bufA, c, r0, 0.0f, q1, q2, o);          // then G2 on cols -> G*V*G2
#pragma unroll
    for (int k = 0; k < 16; ++k) acc += bufU[c * PITCH + r0 + k] * o[k];

    // deterministic block reduction: wave shfl tree, then fixed-order 4-way sum
#pragma unroll
    for (int off = 32; off > 0; off >>= 1)
        acc += __shfl_down(acc, off, 64);
    if ((t & 63) == 0) wsum[t >> 6] = acc;
    __syncthreads();
    if (t == 0) partials[b] = (wsum[0] + wsum[1]) + (wsum[2] + wsum[3]);
}

extern "C" __global__ void __launch_bounds__(64)
reduce_kernel(const float* __restrict__ partials, float* __restrict__ out)
{
    int t = threadIdx.x;
    float v = partials[t];
#pragma unroll
    for (int off = 32; off > 0; off >>= 1)
        v += __shfl_down(v, off, 64);
    if (t == 0) out[0] = v;
}

extern "C" void kernel_launch(void* const* d_in, const int* in_sizes, int n_in,
                              void* d_out, int out_size, void* d_ws, size_t ws_size,
                              hipStream_t stream)
{
    const float* x    = (const float*)d_in[0];
    const float* y    = (const float*)d_in[1];
    const float* cost = (const float*)d_in[2];
    const float* kern = (const float*)d_in[3];
    float* partials   = (float*)d_ws;   // 64 floats

    sinkhorn_kernel<<<64, 256, 0, stream>>>(x, y, cost, kern, partials);
    reduce_kernel<<<1, 64, 0, stream>>>(partials, (float*)d_out);
}

// Round 2
// 86.122 us; speedup vs baseline: 1.6168x; 1.6168x over previous
//
#include <hip/hip_runtime.h>

// Sinkhorn (eps=0.2, 50 iters) on 64x64 images, b=64, via separable banded
// Gibbs kernel: K = G (x) G, G[i,k]=exp(-5(i-k)^2), radius-2 in fp32.
// Structure: per iteration two fused phase-pairs, each = row-conv + intra-wave
// transpose through wave-private LDS scratch (rows [16w,16w+16) of S1 are
// produced AND consumed only by wave w -> lgkmcnt fence, no barrier).
// Only 2 __syncthreads() per iteration (vs 4 before). All LDS reads are
// b64/b128 with immediate offsets; U/V writes are b128; only the transpose
// scatter stays scalar b32 (conflict-free: consecutive addresses across lanes).

#define P 68                 // row pitch in floats: 16B-aligned, bank-floor
#define LDSF (8 + 3 * 4352)  // pad[8] + V + UT + S1  (52,256 B)

__device__ __forceinline__ float frcp_nr(float d) {
    float r = __builtin_amdgcn_rcpf(d);
    return r * fmaf(-d, r, 2.0f);   // 1 Newton step: ~1 ulp
}

__device__ __forceinline__ void loadwin(const float* __restrict__ rp, int c0,
                                        bool lo, bool hi, float* __restrict__ wv) {
    // wv[m] = row[c0-2+m], m=0..19, zero outside [0,64). Halo reads land in
    // row padding / previous buffer tail (in-array, value discarded by select).
    float2 a  = *(const float2*)(rp + c0 - 2);
    float4 b0 = *(const float4*)(rp + c0);
    float4 b1 = *(const float4*)(rp + c0 + 4);
    float4 b2 = *(const float4*)(rp + c0 + 8);
    float4 b3 = *(const float4*)(rp + c0 + 12);
    float2 c  = *(const float2*)(rp + c0 + 16);
    wv[0] = lo ? a.x : 0.0f;  wv[1] = lo ? a.y : 0.0f;
    wv[2]  = b0.x; wv[3]  = b0.y; wv[4]  = b0.z; wv[5]  = b0.w;
    wv[6]  = b1.x; wv[7]  = b1.y; wv[8]  = b1.z; wv[9]  = b1.w;
    wv[10] = b2.x; wv[11] = b2.y; wv[12] = b2.z; wv[13] = b2.w;
    wv[14] = b3.x; wv[15] = b3.y; wv[16] = b3.z; wv[17] = b3.w;
    wv[18] = hi ? c.x : 0.0f; wv[19] = hi ? c.y : 0.0f;
}

__device__ __forceinline__ void conv_g(const float* __restrict__ wv,
                                       float g1, float g2, float* __restrict__ o) {
#pragma unroll
    for (int k = 0; k < 16; ++k)
        o[k] = fmaf(g2, wv[k] + wv[k + 4], fmaf(g1, wv[k + 1] + wv[k + 3], wv[k + 2]));
}

__device__ __forceinline__ void conv_q(const float* __restrict__ wv,
                                       float q1, float q2, float* __restrict__ o) {
#pragma unroll
    for (int k = 0; k < 16; ++k)
        o[k] = fmaf(q2, wv[k] + wv[k + 4], q1 * (wv[k + 1] + wv[k + 3]));
}

#define FENCE() asm volatile("s_waitcnt lgkmcnt(0)" ::: "memory")

extern "C" __global__ void __launch_bounds__(256)
sinkhorn_kernel(const float* __restrict__ x, const float* __restrict__ y,
                const float* __restrict__ cost, const float* __restrict__ kern,
                float* __restrict__ partials)
{
    __shared__ __align__(16) float lds[LDSF];
    float* const Vb = lds + 8;         // V  [i][j]   normal
    float* const UT = Vb + 4352;       // UT [j][i]   = U transposed
    float* const S1 = UT + 4352;       // wave-private scratch (rows [16w,16w+16))

    const int t  = threadIdx.x;
    const int l  = t & 63;
    const int w  = t >> 6;
    const int b  = blockIdx.x;
    const int hq = l >> 2;             // 0..15
    const int q  = l & 3;              // 0..3
    const int j  = 16 * w + hq;        // phase-B row index into S1

    const float g1 = kern[(size_t)64  * 4096];        // e^-5
    const float g2 = kern[(size_t)128 * 4096];        // e^-20
    const float q1 = cost[(size_t)64  * 4096] * g1;   // 1*e^-5
    const float q2 = cost[(size_t)128 * 4096] * g2;   // 4*e^-20

    // marginals at their exact phase-B mappings, kept in registers all 50 iters
    float xv[16], yv[16];
    {
        const float* xb = x + (size_t)b * 4096;
        const float* yb = y + (size_t)b * 4096;
#pragma unroll
        for (int k = 0; k < 16; ++k)
            xv[k] = xb[(16 * q + k) * 64 + j];            // x[i=16q+k][j]
#pragma unroll
        for (int k = 0; k < 16; ++k)
            yv[k] = yb[(size_t)j * 64 + 16 * q + k];      // y[i=j][16q+k]
    }

    // V init = 1/n
    {
        const int r = t >> 2, c0 = 16 * (t & 3);
        const float4 ini = make_float4(1.0f/4096, 1.0f/4096, 1.0f/4096, 1.0f/4096);
        float4* vp = (float4*)(Vb + r * P + c0);
        vp[0] = ini; vp[1] = ini; vp[2] = ini; vp[3] = ini;
    }
    __syncthreads();

    const bool wlo = (w > 0), whi = (w < 3);
    const bool qlo = (q > 0), qhi = (q < 3);
    float wv[20], o[16];

    for (int it = 0; it < 50; ++it) {
        // ---- pair 1: V -> U (stored transposed), uses x ----
        loadwin(Vb + l * P, 16 * w, wlo, whi, wv);     // V row l
        conv_g(wv, g1, g2, o);                          // (V*G)[l][16w+k]
        {
            float* sp = S1 + (16 * w) * P + l;
#pragma unroll
            for (int k = 0; k < 16; ++k) sp[k * P] = o[k];   // S1[16w+k][l]
        }
        FENCE();
        loadwin(S1 + j * P, 16 * q, qlo, qhi, wv);     // S1 row j (own wave)
        conv_g(wv, g1, g2, o);                          // (G*V*G)[16q+k][j]
        {
            float uu[16];
#pragma unroll
            for (int k = 0; k < 16; ++k) uu[k] = xv[k] * frcp_nr(o[k] + 1e-8f);
            float4* up = (float4*)(UT + j * P + 16 * q);
            up[0] = make_float4(uu[0], uu[1], uu[2], uu[3]);
            up[1] = make_float4(uu[4], uu[5], uu[6], uu[7]);
            up[2] = make_float4(uu[8], uu[9], uu[10], uu[11]);
            up[3] = make_float4(uu[12], uu[13], uu[14], uu[15]);
        }
        __syncthreads();
        // ---- pair 2: U -> V (normal), uses y ----
        loadwin(UT + l * P, 16 * w, wlo, whi, wv);     // UT row l = U[:,l]
        conv_g(wv, g1, g2, o);                          // (G*U)[16w+k][l]
        {
            float* sp = S1 + (16 * w) * P + l;
#pragma unroll
            for (int k = 0; k < 16; ++k) sp[k * P] = o[k];   // S1[16w+k][l]
        }
        FENCE();
        loadwin(S1 + j * P, 16 * q, qlo, qhi, wv);     // S1 row j (own wave)
        conv_g(wv, g1, g2, o);                          // (G*U*G)[j][16q+k]
        {
            float vv[16];
#pragma unroll
            for (int k = 0; k < 16; ++k) vv[k] = yv[k] * frcp_nr(o[k] + 1e-8f);
            float4* vp = (float4*)(Vb + j * P + 16 * q);
            vp[0] = make_float4(vv[0], vv[1], vv[2], vv[3]);
            vp[1] = make_float4(vv[4], vv[5], vv[6], vv[7]);
            vp[2] = make_float4(vv[8], vv[9], vv[10], vv[11]);
            vp[3] = make_float4(vv[12], vv[13], vv[14], vv[15]);
        }
        __syncthreads();
    }

    // ---- distance: sum U o (G2*V*G)  +  U o (G*V*G2), two scratch rounds ----
    float acc = 0.0f;
    float um[16];

    loadwin(Vb + l * P, 16 * w, wlo, whi, wv);
    conv_g(wv, g1, g2, o);                              // (V*G)
    {
        float* sp = S1 + (16 * w) * P + l;
#pragma unroll
        for (int k = 0; k < 16; ++k) sp[k * P] = o[k];
    }
    FENCE();
    loadwin(S1 + j * P, 16 * q, qlo, qhi, wv);
    conv_q(wv, q1, q2, o);                              // M1[16q+k][j]
    {
        const float4* up = (const float4*)(UT + j * P + 16 * q);
        float4 u0 = up[0], u1 = up[1], u2 = up[2], u3 = up[3];
        um[0] = u0.x; um[1] = u0.y; um[2]  = u0.z; um[3]  = u0.w;
        um[4] = u1.x; um[5] = u1.y; um[6]  = u1.z; um[7]  = u1.w;
        um[8] = u2.x; um[9] = u2.y; um[10] = u2.z; um[11] = u2.w;
        um[12] = u3.x; um[13] = u3.y; um[14] = u3.z; um[15] = u3.w;
#pragma unroll
        for (int k = 0; k < 16; ++k) acc += um[k] * o[k];
    }
    FENCE();
    loadwin(Vb + l * P, 16 * w, wlo, whi, wv);
    conv_q(wv, q1, q2, o);                              // (V*G2)
    {
        float* sp = S1 + (16 * w) * P + l;
#pragma unroll
        for (int k = 0; k < 16; ++k) sp[k * P] = o[k];
    }
    FENCE();
    loadwin(S1 + j * P, 16 * q, qlo, qhi, wv);
    conv_g(wv, g1, g2, o);                              // M2[16q+k][j]
#pragma unroll
    for (int k = 0; k < 16; ++k) acc += um[k] * o[k];

    // deterministic reduction: wave shfl tree, then fixed-order 4-way sum
#pragma unroll
    for (int off = 32; off > 0; off >>= 1)
        acc += __shfl_down(acc, off, 64);
    if (l == 0) lds[w] = acc;     // pad[0..3]; halo reads only touch pad[6..7]
    __syncthreads();
    if (t == 0) partials[b] = (lds[0] + lds[1]) + (lds[2] + lds[3]);
}

extern "C" __global__ void __launch_bounds__(64)
reduce_kernel(const float* __restrict__ partials, float* __restrict__ out)
{
    int t = threadIdx.x;
    float v = partials[t];
#pragma unroll
    for (int off = 32; off > 0; off >>= 1)
        v += __shfl_down(v, off, 64);
    if (t == 0) out[0] = v;
}

extern "C" void kernel_launch(void* const* d_in, const int* in_sizes, int n_in,
                              void* d_out, int out_size, void* d_ws, size_t ws_size,
                              hipStream_t stream)
{
    const float* x    = (const float*)d_in[0];
    const float* y    = (const float*)d_in[1];
    const float* cost = (const float*)d_in[2];
    const float* kern = (const float*)d_in[3];
    float* partials   = (float*)d_ws;   // 64 floats

    sinkhorn_kernel<<<64, 256, 0, stream>>>(x, y, cost, kern, partials);
    reduce_kernel<<<1, 64, 0, stream>>>(partials, (float*)d_out);
}

// Round 3
// 71.453 us; speedup vs baseline: 1.9487x; 1.2053x over previous
//
#include <hip/hip_runtime.h>

// Sinkhorn (eps=0.2, 50 iters), 64x64 images, b=64. Separable banded Gibbs:
// K = G (x) G, G[i,k]=exp(-5(i-k)^2), radius 2 in fp32.  Each K-matvec =
// col-conv (G*V) then row-conv ((G*V)*G) -- no transpose needed.
// Layout pitch 65: col reads/writes hit bank (l+c)%32 (2-way = free, m136);
// row reads hit (hq+8q+c)%32 (2-way = free). All LDS base addresses are
// loop-invariant -> pure ds_read_b32/ds_write_b32 with immediate offsets.
// 512 threads = 8 waves; wave w owns scratch rows [8w,8w+8) in BOTH phases,
// so phase1->phase2 handoff is a wave-private lgkmcnt fence; only the +-2-row
// halo across pairs needs __syncthreads (2 barriers + 2 fences / iter).

#define ROWP 65
#define BUF  (ROWP * 64)   // 4160 floats
#define GAP  132           // >= 2*ROWP halo pad around each buffer

#define FENCE() asm volatile("s_waitcnt lgkmcnt(0)" ::: "memory")

__device__ __forceinline__ float frcp_nr(float d) {
    float r = __builtin_amdgcn_rcpf(d);
    return r * fmaf(-d, r, 2.0f);   // 1 Newton step: ~1 ulp
}

// 12-tap window read, column direction (stride ROWP), edges zeroed by select
__device__ __forceinline__ void win_col(const float* __restrict__ rp,
                                        bool lo, bool hi, float* __restrict__ wv) {
#pragma unroll
    for (int m = 0; m < 12; ++m) wv[m] = rp[ROWP * m];
    wv[0]  = lo ? wv[0]  : 0.0f;  wv[1]  = lo ? wv[1]  : 0.0f;
    wv[10] = hi ? wv[10] : 0.0f;  wv[11] = hi ? wv[11] : 0.0f;
}

// 12-tap window read, row direction (stride 1)
__device__ __forceinline__ void win_row(const float* __restrict__ rp,
                                        bool lo, bool hi, float* __restrict__ wv) {
#pragma unroll
    for (int m = 0; m < 12; ++m) wv[m] = rp[m];
    wv[0]  = lo ? wv[0]  : 0.0f;  wv[1]  = lo ? wv[1]  : 0.0f;
    wv[10] = hi ? wv[10] : 0.0f;  wv[11] = hi ? wv[11] : 0.0f;
}

__device__ __forceinline__ void conv_g(const float* __restrict__ wv,
                                       float g1, float g2, float* __restrict__ o) {
#pragma unroll
    for (int k = 0; k < 8; ++k) {
        float s2 = wv[k] + wv[k + 4], s1 = wv[k + 1] + wv[k + 3];
        o[k] = fmaf(g2, s2, fmaf(g1, s1, wv[k + 2]));
    }
}

__device__ __forceinline__ void conv_q(const float* __restrict__ wv,
                                       float q1, float q2, float* __restrict__ o) {
#pragma unroll
    for (int k = 0; k < 8; ++k) {
        float s2 = wv[k] + wv[k + 4], s1 = wv[k + 1] + wv[k + 3];
        o[k] = fmaf(q2, s2, q1 * s1);
    }
}

extern "C" __global__ void __launch_bounds__(512)
sinkhorn_kernel(const float* __restrict__ x, const float* __restrict__ y,
                const float* __restrict__ cost, const float* __restrict__ kern,
                float* __restrict__ partials)
{
    __shared__ float lds[GAP + BUF + GAP + BUF + GAP + BUF + GAP + 8];
    float* const V = lds + GAP;
    float* const A = V + BUF + GAP;        // scratch: wave w owns rows [8w,8w+8)
    float* const U = A + BUF + GAP;
    float* const wsum = U + BUF + GAP;

    const int t  = threadIdx.x;
    const int l  = t & 63;
    const int w  = t >> 6;        // wave 0..7
    const int hq = l >> 3;        // 0..7
    const int q  = l & 7;         // 0..7
    const int r  = 8 * w + hq;    // phase-2 row (in wave w's block)
    const int b  = blockIdx.x;

    const float g1 = kern[(size_t)64  * 4096];        // e^-5
    const float g2 = kern[(size_t)128 * 4096];        // e^-20
    const float q1 = cost[(size_t)64  * 4096] * g1;   // 1*e^-5
    const float q2 = cost[(size_t)128 * 4096] * g2;   // 4*e^-20

    // loop-invariant LDS addresses (ds_* with immediate offsets inside loop)
    float* const rV1 = V + ROWP * (8 * w - 2) + l;    // ph1 read V  [ROWP*m]
    float* const rU1 = U + ROWP * (8 * w - 2) + l;    // ph1 read U  [ROWP*m]
    float* const wA1 = A + ROWP * (8 * w) + l;        // ph1 write A [ROWP*k]
    float* const rA2 = A + ROWP * r + 8 * q - 2;      // ph2 read A  [m]
    float* const wU2 = U + ROWP * r + 8 * q;          // ph2 write U [k]
    float* const wV2 = V + ROWP * r + 8 * q;          // ph2 write V [k]

    const bool wlo = (w > 0), whi = (w < 7);
    const bool qlo = (q > 0), qhi = (q < 7);

    // marginals at the phase-2 mapping, in registers for all 50 iters
    float xv[8], yv[8];
    {
        const float* xb = x + (size_t)b * 4096 + 64 * r + 8 * q;
        const float* yb = y + (size_t)b * 4096 + 64 * r + 8 * q;
#pragma unroll
        for (int k = 0; k < 8; ++k) xv[k] = xb[k];
#pragma unroll
        for (int k = 0; k < 8; ++k) yv[k] = yb[k];
    }

    // V init = 1/n
    {
        float* vp = V + ROWP * (t >> 3) + 8 * (t & 7);
#pragma unroll
        for (int k = 0; k < 8; ++k) vp[k] = 1.0f / 4096.0f;
    }
    __syncthreads();

    float wv[12], o[8];

#pragma unroll 1
    for (int it = 0; it < 50; ++it) {
        // ---- pair 1:  A = G*V (col conv);  U = x / (A*G + 1e-8) (row conv)
        win_col(rV1, wlo, whi, wv);
        conv_g(wv, g1, g2, o);
#pragma unroll
        for (int k = 0; k < 8; ++k) wA1[ROWP * k] = o[k];
        FENCE();
        win_row(rA2, qlo, qhi, wv);
        conv_g(wv, g1, g2, o);
#pragma unroll
        for (int k = 0; k < 8; ++k) wU2[k] = xv[k] * frcp_nr(o[k] + 1e-8f);
        __syncthreads();

        // ---- pair 2:  A = G*U;  V = y / (A*G + 1e-8)
        win_col(rU1, wlo, whi, wv);
        conv_g(wv, g1, g2, o);
#pragma unroll
        for (int k = 0; k < 8; ++k) wA1[ROWP * k] = o[k];
        FENCE();
        win_row(rA2, qlo, qhi, wv);
        conv_g(wv, g1, g2, o);
#pragma unroll
        for (int k = 0; k < 8; ++k) wV2[k] = yv[k] * frcp_nr(o[k] + 1e-8f);
        __syncthreads();
    }

    // ---- distance: sum U o (G2*V*G) + sum U o (G*V*G2)
    float acc = 0.0f, um[8];
#pragma unroll
    for (int k = 0; k < 8; ++k) um[k] = wU2[k];   // U at this thread's tile

    // M1 = (G2*V)*G
    win_col(rV1, wlo, whi, wv);
    conv_q(wv, q1, q2, o);
#pragma unroll
    for (int k = 0; k < 8; ++k) wA1[ROWP * k] = o[k];
    FENCE();
    win_row(rA2, qlo, qhi, wv);
    conv_g(wv, g1, g2, o);
#pragma unroll
    for (int k = 0; k < 8; ++k) acc = fmaf(um[k], o[k], acc);

    FENCE();   // one-time safety: A reads drained before overwrite
    // M2 = (G*V)*G2
    win_col(rV1, wlo, whi, wv);
    conv_g(wv, g1, g2, o);
#pragma unroll
    for (int k = 0; k < 8; ++k) wA1[ROWP * k] = o[k];
    FENCE();
    win_row(rA2, qlo, qhi, wv);
    conv_q(wv, q1, q2, o);
#pragma unroll
    for (int k = 0; k < 8; ++k) acc = fmaf(um[k], o[k], acc);

    // deterministic reduction: wave shfl tree, then fixed-order 8-way sum
#pragma unroll
    for (int off = 32; off > 0; off >>= 1)
        acc += __shfl_down(acc, off, 64);
    if (l == 0) wsum[w] = acc;
    __syncthreads();
    if (t == 0) {
        float s = ((wsum[0] + wsum[1]) + (wsum[2] + wsum[3]))
                + ((wsum[4] + wsum[5]) + (wsum[6] + wsum[7]));
        partials[b] = s;
    }
}

extern "C" __global__ void __launch_bounds__(64)
reduce_kernel(const float* __restrict__ partials, float* __restrict__ out)
{
    int t = threadIdx.x;
    float v = partials[t];
#pragma unroll
    for (int off = 32; off > 0; off >>= 1)
        v += __shfl_down(v, off, 64);
    if (t == 0) out[0] = v;
}

extern "C" void kernel_launch(void* const* d_in, const int* in_sizes, int n_in,
                              void* d_out, int out_size, void* d_ws, size_t ws_size,
                              hipStream_t stream)
{
    const float* x    = (const float*)d_in[0];
    const float* y    = (const float*)d_in[1];
    const float* cost = (const float*)d_in[2];
    const float* kern = (const float*)d_in[3];
    float* partials   = (float*)d_ws;   // 64 floats

    sinkhorn_kernel<<<64, 512, 0, stream>>>(x, y, cost, kern, partials);
    reduce_kernel<<<1, 64, 0, stream>>>(partials, (float*)d_out);
}